// Round 6
// baseline (169.378 us; speedup 1.0000x reference)
//
#include <hip/hip_runtime.h>
#include <stdint.h>

#define SEQ  2048
#define DIMC 256
#define HID  512
#define NH   8
#define DH   64

typedef __attribute__((ext_vector_type(8))) short bf16x8;
typedef __attribute__((ext_vector_type(4))) float f32x4;
typedef __attribute__((ext_vector_type(16))) float f32x16;
typedef __attribute__((ext_vector_type(2))) unsigned uint2v;
typedef __attribute__((address_space(1))) const uint32_t guint_t;
typedef __attribute__((address_space(3))) uint32_t luint_t;

// async global->LDS, 16B per lane; LDS dest = wave-uniform base + lane*16
__device__ __forceinline__ void gld16(const void* g, void* l) {
  __builtin_amdgcn_global_load_lds((guint_t*)g, (luint_t*)l, 16, 0, 0);
}

__device__ __forceinline__ uint32_t fbits(float f) {
  union { float f; uint32_t u; } v; v.f = f; return v.u;
}
__device__ __forceinline__ unsigned short f2bf(float f) {   // RNE-ish
  uint32_t u = fbits(f);
  return (unsigned short)((u + 0x7FFFu + ((u >> 16) & 1u)) >> 16);
}
__device__ __forceinline__ unsigned short f2bf_fast(float f) {  // round-half-up
  return (unsigned short)((fbits(f) + 0x8000u) >> 16);
}
// pack two fp32 (raw bits) -> (bf16,bf16) dword, round-half-up
__device__ __forceinline__ uint32_t pku(uint32_t u0, uint32_t u1) {
  return __builtin_amdgcn_perm(u1 + 0x8000u, u0 + 0x8000u, 0x07060302u);
}

// exchange hi 32 lanes of a with lo 32 lanes of b
__device__ __forceinline__ void swap32(uint32_t& a, uint32_t& b) {
#if __has_builtin(__builtin_amdgcn_permlane32_swap)
  uint2v r = __builtin_amdgcn_permlane32_swap(a, b, false, false);
  a = r[0]; b = r[1];
#else
  uint32_t aw = __shfl_xor(a, 32);
  uint32_t bw = __shfl_xor(b, 32);
  bool lo = (threadIdx.x & 32) == 0;
  uint32_t an = lo ? a : bw;
  uint32_t bn = lo ? aw : b;
  a = an; b = bn;
#endif
}

// ---------------------------------------------------------------------------
// qkv_gemm (prep folded in): A = wqkv fp32 (convert + Q-scale during staging),
// B = x fp32 [k][n] (convert + transpose during staging; bank-checked 2-way).
// 128x128 tile, BK=64. Epilogue: Q,K -> [bh][n][64]; V -> [bh][64][n].
// ---------------------------------------------------------------------------
__global__ __launch_bounds__(256, 2) void qkv_gemm(
    const float* __restrict__ wqkv, const float* __restrict__ x,
    unsigned short* __restrict__ Qs, unsigned short* __restrict__ Ks,
    unsigned short* __restrict__ Vt) {
  __shared__ unsigned short lds[17408];   // la 128*64, lb 128*64; epilogue 128*136
  unsigned short* la = lds;
  unsigned short* lb = lds + 8192;
  int o0 = blockIdx.x * 128;
  int n0 = blockIdx.y * 128;
  int b  = blockIdx.z;
  int t  = threadIdx.x;
  int wv = t >> 6, l = t & 63, l15 = l & 15, q = l >> 4;
  int wm = (wv & 1) * 64, wn = (wv >> 1) * 64;
  float sc = (o0 < HID) ? 0.18033688011112042f : 1.0f;   // 0.125*log2(e) on Q rows
  f32x4 acc[4][4];
#pragma unroll
  for (int i = 0; i < 4; i++)
#pragma unroll
    for (int j = 0; j < 4; j++) acc[i][j] = (f32x4){0.f, 0.f, 0.f, 0.f};
  const float* Ag = wqkv + (size_t)o0 * DIMC;
  const float* Bx = x + (size_t)b * DIMC * SEQ;      // [k][n]
  int rowA = t >> 1, halfA = t & 1;
  for (int kk = 0; kk < 4; kk++) {
    int k0 = kk * 64;
    __syncthreads();
    // ---- A tile: 128 rows x 64 k fp32 -> bf16, swizzled 16B granules ----
    {
      const float* src = Ag + (size_t)rowA * DIMC + k0 + halfA * 32;
      float4 f[8];
#pragma unroll
      for (int j = 0; j < 8; j++) f[j] = ((const float4*)src)[j];
#pragma unroll
      for (int jj = 0; jj < 4; jj++) {
        uint4 o;
        o.x = pku(fbits(f[2*jj].x * sc),   fbits(f[2*jj].y * sc));
        o.y = pku(fbits(f[2*jj].z * sc),   fbits(f[2*jj].w * sc));
        o.z = pku(fbits(f[2*jj+1].x * sc), fbits(f[2*jj+1].y * sc));
        o.w = pku(fbits(f[2*jj+1].z * sc), fbits(f[2*jj+1].w * sc));
        int s = halfA * 4 + jj;
        *(uint4*)(la + rowA * 64 + ((s ^ (rowA & 7)) * 8)) = o;
      }
    }
    // ---- B tile: x[k0..+64][n0..+128] -> lb[n][k] bf16 transpose ----
    {
      int k = l;                      // lane = k row (scattered 16B loads, L2-hot)
      const float* src = Bx + (size_t)(k0 + k) * SEQ + n0 + wv * 32;
      int s = k >> 3, k7 = k & 7;
#pragma unroll
      for (int j = 0; j < 8; j++) {
        float4 f = ((const float4*)src)[j];
        int n = wv * 32 + j * 4;
        lb[(n+0) * 64 + ((s ^ ((n+0) & 7)) * 8) + k7] = f2bf_fast(f.x);
        lb[(n+1) * 64 + ((s ^ ((n+1) & 7)) * 8) + k7] = f2bf_fast(f.y);
        lb[(n+2) * 64 + ((s ^ ((n+2) & 7)) * 8) + k7] = f2bf_fast(f.z);
        lb[(n+3) * 64 + ((s ^ ((n+3) & 7)) * 8) + k7] = f2bf_fast(f.w);
      }
    }
    __syncthreads();
#pragma unroll
    for (int kh = 0; kh < 2; kh++) {
      bf16x8 af[4], bfr[4];
#pragma unroll
      for (int mt = 0; mt < 4; mt++) {
        int row = wm + mt*16 + l15;
        af[mt] = *(const bf16x8*)(la + row*64 + ((kh*4 + q) ^ (row & 7)) * 8);
      }
#pragma unroll
      for (int nt = 0; nt < 4; nt++) {
        int row = wn + nt*16 + l15;
        bfr[nt] = *(const bf16x8*)(lb + row*64 + ((kh*4 + q) ^ (row & 7)) * 8);
      }
#pragma unroll
      for (int mt = 0; mt < 4; mt++)
#pragma unroll
        for (int nt = 0; nt < 4; nt++)
          acc[mt][nt] = __builtin_amdgcn_mfma_f32_16x16x32_bf16(af[mt], bfr[nt], acc[mt][nt], 0, 0, 0);
    }
  }
  __syncthreads();
  int seg3 = o0 >> 9;            // 0=Q, 1=K, 2=V
  int h0   = (o0 & 511) >> 6;
  if (seg3 == 2) {
#pragma unroll
    for (int mt = 0; mt < 4; mt++)
#pragma unroll
      for (int nt = 0; nt < 4; nt++)
#pragma unroll
        for (int r = 0; r < 4; r++) {
          int ol = wm + mt * 16 + q * 4 + r;
          int h = h0 + (ol >> 6), d = ol & 63;
          int n = n0 + wn + nt * 16 + l15;
          Vt[(((size_t)b * NH + h) * DH + d) * SEQ + n] = f2bf(acc[mt][nt][r]);
        }
  } else {
    unsigned short* dst = (seg3 == 0) ? Qs : Ks;
#pragma unroll
    for (int mt = 0; mt < 4; mt++)
#pragma unroll
      for (int nt = 0; nt < 4; nt++)
#pragma unroll
        for (int r = 0; r < 4; r++) {
          int ol = wm + mt * 16 + q * 4 + r;
          int nn = wn + nt * 16 + l15;
          lds[nn * 136 + ol] = f2bf(acc[mt][nt][r]);
        }
    __syncthreads();
#pragma unroll
    for (int i = 0; i < 8; i++) {
      int idx = i * 256 + t;
      int nn  = idx >> 4;
      int olb = (idx & 15) * 8;
      uint4 v = *(const uint4*)(lds + nn * 136 + olb);
      int h = h0 + (olb >> 6), d = olb & 63;
      *(uint4*)(dst + (((size_t)b * NH + h) * SEQ + n0 + nn) * DH + d) = v;
    }
  }
}

// ---------------------------------------------------------------------------
// attn: 512 threads = 8 waves = (qg in {0,1}) x (cg in {0..3}).
// Wave: 64 queries x 512 keys, 32x32x16 MFMA, register P-transform.
// Double-buffered 32-key K/V LDS tiles via gld16 (wave w<4 stages K-chunk w,
// w>=4 stages V-chunk w-4). Additive partials; LDS tree-combine at end.
// launch_bounds(512,2): 2 blocks/CU -> VGPR<=128, 4 waves/SIMD.
// ---------------------------------------------------------------------------
__global__ __launch_bounds__(512, 2) void attn_kernel(
    const unsigned short* __restrict__ Qs, const unsigned short* __restrict__ Ks,
    const unsigned short* __restrict__ Vt, unsigned short* __restrict__ AO) {
  __shared__ unsigned short KV[32768];  // 2 bufs x (K: 4x2048, V: 4x2048) shorts
  __shared__ float Lc[512];             // [cg][128 q] row-sum partials
  int n0 = blockIdx.x * 128;
  int bh = blockIdx.y;
  int b = bh >> 3, h = bh & 7;
  int t = threadIdx.x;
  int w = t >> 6, l = t & 63, l31 = l & 31, lh = l >> 5;
  int sc_ = w & 3;                  // kv chunk (also the chunk this wave stages)
  int qg  = w >> 2;                 // query group
  int stgK = (w < 4);
  // Q B-frags from global, once
  const unsigned short* Qg = Qs + ((size_t)bh * SEQ + n0 + qg * 64) * DH;
  bf16x8 qb[2][4];
#pragma unroll
  for (int qt = 0; qt < 2; qt++)
#pragma unroll
    for (int kc = 0; kc < 4; kc++)
      qb[qt][kc] = *(const bf16x8*)(Qg + (qt*32 + l31) * DH + kc*16 + lh*8);
  f32x16 oacc[2][2];
  float lrowp[2] = {0.f, 0.f};
#pragma unroll
  for (int qt = 0; qt < 2; qt++)
#pragma unroll
    for (int dt = 0; dt < 2; dt++)
#pragma unroll
      for (int r = 0; r < 16; r++) oacc[qt][dt][r] = 0.f;
  const unsigned short* Kgs = Ks + ((size_t)bh * SEQ + sc_ * 512) * DH;
  const unsigned short* Vgs = Vt + (size_t)bh * DH * SEQ + sc_ * 512;
  int hv = 0;  // (recomputed per use)
  auto stage = [&](int it, int buf) {
    unsigned short* base = KV + buf * 16384 + sc_ * 2048 + (stgK ? 0 : 8192);
    if (stgK) {
#pragma unroll
      for (int g = 0; g < 4; g++) {
        int kr = g * 8 + (l >> 3);
        gld16(Kgs + (size_t)(it*32 + kr) * DH + ((l & 7) ^ (kr & 7)) * 8,
              base + g * 512);
      }
    } else {
#pragma unroll
      for (int g = 0; g < 4; g++) {
        int dr = g * 16 + (l >> 2);
        int seg = (l & 3) ^ ((dr ^ (dr >> 2)) & 3);
        gld16(Vgs + (size_t)dr * SEQ + it*32 + seg * 8, base + g * 512);
      }
    }
  };
  stage(0, 0);
  __syncthreads();
  for (int it = 0; it < 16; it++) {
    if (it + 1 < 16) stage(it + 1, (it + 1) & 1);
    const unsigned short* Kb = KV + (it & 1) * 16384 + sc_ * 2048;
    const unsigned short* Vb = Kb + 8192;
    // S^T = K Q^T : D[m=key(rows)][n=query(col=l31)]
    f32x16 st[2];
#pragma unroll
    for (int qt = 0; qt < 2; qt++)
#pragma unroll
      for (int r = 0; r < 16; r++) st[qt][r] = 0.f;
#pragma unroll
    for (int kc = 0; kc < 4; kc++) {
      bf16x8 kf = *(const bf16x8*)(Kb + l31 * 64 + (((kc*2 + lh) ^ (l31 & 7))) * 8);
      st[0] = __builtin_amdgcn_mfma_f32_32x32x16_bf16(kf, qb[0][kc], st[0], 0, 0, 0);
      st[1] = __builtin_amdgcn_mfma_f32_32x32x16_bf16(kf, qb[1][kc], st[1], 0, 0, 0);
    }
    bf16x8 vf[2][2];
#pragma unroll
    for (int kc2 = 0; kc2 < 2; kc2++)
#pragma unroll
      for (int dt = 0; dt < 2; dt++) {
        int d = dt*32 + l31;
        hv = (d ^ (d >> 2)) & 3;
        vf[kc2][dt] = *(const bf16x8*)(Vb + d * 32 + (((kc2*2 + lh) ^ hv)) * 8);
      }
#pragma unroll
    for (int qt = 0; qt < 2; qt++) {
      float p[16];
      float s0 = 0.f;
#pragma unroll
      for (int r = 0; r < 16; r++) { p[r] = __builtin_amdgcn_exp2f(st[qt][r]); s0 += p[r]; }
      lrowp[qt] += s0;
      bf16x8 af[2];
#pragma unroll
      for (int hf = 0; hf < 2; hf++) {
        uint32_t xs[4], ys[4];
#pragma unroll
        for (int j = 0; j < 4; j++) {
          xs[j] = fbits(p[hf*8 + j]);
          ys[j] = fbits(p[hf*8 + 4 + j]);
          swap32(xs[j], ys[j]);
        }
        union { uint32_t u[4]; bf16x8 v; } cv;
        cv.u[0] = pku(xs[0], xs[1]);
        cv.u[1] = pku(xs[2], xs[3]);
        cv.u[2] = pku(ys[0], ys[1]);
        cv.u[3] = pku(ys[2], ys[3]);
        af[hf] = cv.v;
      }
#pragma unroll
      for (int kc2 = 0; kc2 < 2; kc2++)
#pragma unroll
        for (int dt = 0; dt < 2; dt++)
          oacc[qt][dt] = __builtin_amdgcn_mfma_f32_32x32x16_bf16(af[kc2], vf[kc2][dt], oacc[qt][dt], 0, 0, 0);
    }
    __syncthreads();
  }
  // ---- combine 4 additive kv-chunk partials ----
#pragma unroll
  for (int qt = 0; qt < 2; qt++) {
    float v = lrowp[qt];
    v += __shfl_xor(v, 32);
    if (l < 32) Lc[sc_ * 128 + qg * 64 + qt * 32 + l31] = v;
  }
  float* Ocf = (float*)KV;
  auto dump = [&](float* R) {
#pragma unroll
    for (int qt = 0; qt < 2; qt++)
#pragma unroll
      for (int dt = 0; dt < 2; dt++)
#pragma unroll
        for (int rr = 0; rr < 4; rr++)
          *(f32x4*)(R + ((qt*2+dt)*4 + rr) * 256 + l * 4) =
            (f32x4){oacc[qt][dt][rr*4+0], oacc[qt][dt][rr*4+1],
                    oacc[qt][dt][rr*4+2], oacc[qt][dt][rr*4+3]};
  };
  auto addin = [&](const float* R) {
#pragma unroll
    for (int qt = 0; qt < 2; qt++)
#pragma unroll
      for (int dt = 0; dt < 2; dt++)
#pragma unroll
        for (int rr = 0; rr < 4; rr++) {
          f32x4 v = *(const f32x4*)(R + ((qt*2+dt)*4 + rr) * 256 + l * 4);
          oacc[qt][dt][rr*4+0] += v[0]; oacc[qt][dt][rr*4+1] += v[1];
          oacc[qt][dt][rr*4+2] += v[2]; oacc[qt][dt][rr*4+3] += v[3];
        }
  };
  if (sc_ & 1) dump(Ocf + qg * 8192 + (sc_ >> 1) * 4096);
  __syncthreads();
  if (!(sc_ & 1)) addin(Ocf + qg * 8192 + (sc_ >> 1) * 4096);
  __syncthreads();
  if (sc_ == 2) dump(Ocf + qg * 8192);
  __syncthreads();
  if (sc_ == 0) {
    addin(Ocf + qg * 8192);
    unsigned short* AOb = AO + (size_t)b * SEQ * HID + h * DH;
#pragma unroll
    for (int qt = 0; qt < 2; qt++)
#pragma unroll
      for (int r = 0; r < 16; r++) {
        int qrow = qg*64 + qt*32 + (r & 3) + 8*(r >> 2) + 4*lh;
        float lsum = Lc[qrow] + Lc[128 + qrow] + Lc[256 + qrow] + Lc[384 + qrow];
        float inv = __builtin_amdgcn_rcpf(lsum);
        int n = n0 + qrow;
#pragma unroll
        for (int dt = 0; dt < 2; dt++)
          AOb[(size_t)n * HID + dt*32 + l31] = f2bf(oacc[qt][dt][r] * inv);
      }
  }
}

// ---------------------------------------------------------------------------
// out_gemm (prep folded): A = wout fp32 (convert during staging), B = AO bf16
// via gld16. 64x64 tile, grid 512 = 2 blocks/CU. fp32 out + bias.
// ---------------------------------------------------------------------------
__global__ __launch_bounds__(256, 2) void out_gemm(
    const float* __restrict__ wo, const unsigned short* __restrict__ AO,
    const float* __restrict__ bias, float* __restrict__ out) {
  __shared__ unsigned short la[64 * 64];
  __shared__ unsigned short lb[64 * 64];
  int o0 = blockIdx.x * 64;
  int n0 = blockIdx.y * 64;
  int b  = blockIdx.z;
  int t  = threadIdx.x;
  int wv = t >> 6, l = t & 63, l15 = l & 15, q = l >> 4;
  int wm = (wv & 1) * 32, wn = (wv >> 1) * 32;
  f32x4 acc[2][2];
#pragma unroll
  for (int i = 0; i < 2; i++)
#pragma unroll
    for (int j = 0; j < 2; j++) acc[i][j] = (f32x4){0.f,0.f,0.f,0.f};
  const float* Ag = wo + (size_t)o0 * HID;
  const unsigned short* Bg = AO + ((size_t)b * SEQ + n0) * HID;
  int rowA = t >> 2, q4 = t & 3;
  for (int kk = 0; kk < 8; kk++) {
    int k0 = kk * 64;
    __syncthreads();
    // A: 64x64 fp32 -> bf16 swizzled
    {
      const float* src = Ag + (size_t)rowA * HID + k0 + q4 * 16;
      float4 f[4];
#pragma unroll
      for (int j = 0; j < 4; j++) f[j] = ((const float4*)src)[j];
#pragma unroll
      for (int jj = 0; jj < 2; jj++) {
        uint4 o;
        o.x = pku(fbits(f[2*jj].x),   fbits(f[2*jj].y));
        o.y = pku(fbits(f[2*jj].z),   fbits(f[2*jj].w));
        o.z = pku(fbits(f[2*jj+1].x), fbits(f[2*jj+1].y));
        o.w = pku(fbits(f[2*jj+1].z), fbits(f[2*jj+1].w));
        int s = q4 * 2 + jj;
        *(uint4*)(la + rowA * 64 + ((s ^ (rowA & 7)) * 8)) = o;
      }
    }
    // B: AO bf16 via gld16, 8 chunks of 8 rows
#pragma unroll
    for (int c0 = 0; c0 < 2; c0++) {
      int c = wv * 2 + c0;
      int row = c * 8 + (l >> 3);
      int sg = (l & 7) ^ (row & 7);
      gld16(Bg + (size_t)row * HID + k0 + sg * 8, lb + c * 512);
    }
    __syncthreads();
#pragma unroll
    for (int kh = 0; kh < 2; kh++) {
      bf16x8 af[2], bfr[2];
#pragma unroll
      for (int mt = 0; mt < 2; mt++) {
        int row = wm + mt*16 + l15;
        af[mt] = *(const bf16x8*)(la + row*64 + ((kh*4 + q) ^ (row & 7)) * 8);
      }
#pragma unroll
      for (int nt = 0; nt < 2; nt++) {
        int row = wn + nt*16 + l15;
        bfr[nt] = *(const bf16x8*)(lb + row*64 + ((kh*4 + q) ^ (row & 7)) * 8);
      }
#pragma unroll
      for (int mt = 0; mt < 2; mt++)
#pragma unroll
        for (int nt = 0; nt < 2; nt++)
          acc[mt][nt] = __builtin_amdgcn_mfma_f32_16x16x32_bf16(af[mt], bfr[nt], acc[mt][nt], 0,0,0);
    }
  }
#pragma unroll
  for (int mt = 0; mt < 2; mt++)
#pragma unroll
    for (int nt = 0; nt < 2; nt++)
#pragma unroll
      for (int r = 0; r < 4; r++) {
        int o2 = o0 + wm + mt*16 + q*4 + r;
        int n  = n0 + wn + nt*16 + l15;
        out[((size_t)b * DIMC + o2) * SEQ + n] = acc[mt][nt][r] + bias[o2];
      }
}

extern "C" void kernel_launch(void* const* d_in, const int* in_sizes, int n_in,
                              void* d_out, int out_size, void* d_ws, size_t ws_size,
                              hipStream_t stream) {
  const float* x    = (const float*)d_in[0];
  const float* wqkv = (const float*)d_in[1];
  const float* wout = (const float*)d_in[2];
  const float* bout = (const float*)d_in[3];
  float* out = (float*)d_out;
  char* ws = (char*)d_ws;
  unsigned short* Qs = (unsigned short*)(ws);                // 8388608 B
  unsigned short* Ks = (unsigned short*)(ws + 8388608);      // 8388608 B
  unsigned short* Vt = (unsigned short*)(ws + 16777216);     // 8388608 B
  unsigned short* AO = (unsigned short*)(ws + 25165824);     // 8388608 B
  qkv_gemm<<<dim3(12, 16, 4), 256, 0, stream>>>(wqkv, x, Qs, Ks, Vt);
  attn_kernel<<<dim3(16, 32), 512, 0, stream>>>(Qs, Ks, Vt, AO);
  out_gemm<<<dim3(4, 32, 4), 256, 0, stream>>>(wout, AO, bout, out);
}